// Round 1
// baseline (7663.557 us; speedup 1.0000x reference)
//
#include <hip/hip_runtime.h>

#define N_NODES 50000
#define N_EDGES 800000
#define IN_CH 128
#define HID 256
#define N_GRAPHS 64
#define N_CLASSES 10

// ---------------------------------------------------------------------------
// agg[dst[e], :] += feat[src[e], :]   (feature dim d, multiple of 4)
// thread t handles one float4 chunk of one edge; d4 consecutive threads
// read one feature row contiguously (coalesced 512B/1KB row reads).
// ---------------------------------------------------------------------------
__global__ void scatter_add_kernel(const float* __restrict__ feat,
                                   const int* __restrict__ src,
                                   const int* __restrict__ dst,
                                   float* __restrict__ agg,
                                   int d, int d4, long long total)
{
    long long t = (long long)blockIdx.x * blockDim.x + threadIdx.x;
    if (t >= total) return;
    int e = (int)(t / d4);
    int c = (int)(t % d4) * 4;
    int s  = src[e];
    int dd = dst[e];
    const float4 v = *reinterpret_cast<const float4*>(feat + (long long)s * d + c);
    float* out = agg + (long long)dd * d + c;
    atomicAdd(out + 0, v.x);
    atomicAdd(out + 1, v.y);
    atomicAdd(out + 2, v.z);
    atomicAdd(out + 3, v.w);
}

// ---------------------------------------------------------------------------
// C[i,j] = act( A1[i,:]@B1[:,j] + A2[i,:]@B2[:,j] + bias[j] )
// A1,A2: [M,K] row-major; B1,B2: [K,Ncols] row-major; C: [M,Ncols].
// 64x64 tile per 256-thread block, 4x4 outputs per thread, BK=16.
// ---------------------------------------------------------------------------
template<int RELU>
__global__ void __launch_bounds__(256)
gconv_gemm_kernel(const float* __restrict__ A1, const float* __restrict__ A2,
                  const float* __restrict__ B1, const float* __restrict__ B2,
                  const float* __restrict__ bias,
                  float* __restrict__ C,
                  int M, int K, int Ncols)
{
    __shared__ float As[16][68];   // A tile transposed: As[k][m]; 68 keeps rows 16B-aligned
    __shared__ float Bs[16][64];   // B tile: Bs[k][n]

    const int tid = threadIdx.x;
    const int bm = blockIdx.x * 64;
    const int bn = blockIdx.y * 64;
    const int ty = tid >> 4;      // 0..15 -> output rows ty*4..ty*4+3
    const int tx = tid & 15;      // 0..15 -> output cols tx*4..tx*4+3

    float acc[4][4] = {};

    for (int mat = 0; mat < 2; ++mat) {
        const float* __restrict__ A = mat ? A2 : A1;
        const float* __restrict__ B = mat ? B2 : B1;
        for (int k0 = 0; k0 < K; k0 += 16) {
            // --- load A tile (64 rows x 16 k) ---
            {
                int m  = tid >> 2;            // 0..63
                int k4 = (tid & 3) * 4;       // 0,4,8,12
                int row = bm + m;
                float4 v = make_float4(0.f, 0.f, 0.f, 0.f);
                if (row < M)
                    v = *reinterpret_cast<const float4*>(A + (long long)row * K + k0 + k4);
                As[k4 + 0][m] = v.x;
                As[k4 + 1][m] = v.y;
                As[k4 + 2][m] = v.z;
                As[k4 + 3][m] = v.w;
            }
            // --- load B tile (16 k x 64 cols) ---
            {
                int k  = tid >> 4;            // 0..15
                int n4 = (tid & 15) * 4;      // 0..60
                float4 v = *reinterpret_cast<const float4*>(B + (long long)(k0 + k) * Ncols + bn + n4);
                *reinterpret_cast<float4*>(&Bs[k][n4]) = v;
            }
            __syncthreads();
            #pragma unroll
            for (int kk = 0; kk < 16; ++kk) {
                float4 a = *reinterpret_cast<const float4*>(&As[kk][ty * 4]);
                float4 b = *reinterpret_cast<const float4*>(&Bs[kk][tx * 4]);
                acc[0][0] += a.x * b.x; acc[0][1] += a.x * b.y; acc[0][2] += a.x * b.z; acc[0][3] += a.x * b.w;
                acc[1][0] += a.y * b.x; acc[1][1] += a.y * b.y; acc[1][2] += a.y * b.z; acc[1][3] += a.y * b.w;
                acc[2][0] += a.z * b.x; acc[2][1] += a.z * b.y; acc[2][2] += a.z * b.z; acc[2][3] += a.z * b.w;
                acc[3][0] += a.w * b.x; acc[3][1] += a.w * b.y; acc[3][2] += a.w * b.z; acc[3][3] += a.w * b.w;
            }
            __syncthreads();
        }
    }

    // --- epilogue: bias (+ relu), store ---
    #pragma unroll
    for (int i = 0; i < 4; ++i) {
        int row = bm + ty * 4 + i;
        if (row >= M) continue;
        #pragma unroll
        for (int j = 0; j < 4; ++j) {
            int col = bn + tx * 4 + j;
            float v = acc[i][j] + bias[col];
            if (RELU) v = fmaxf(v, 0.f);
            C[(long long)row * Ncols + col] = v;
        }
    }
}

// ---------------------------------------------------------------------------
// pooled[batch[i], :] += h[i, :]; counts[batch[i]] += 1
// ---------------------------------------------------------------------------
__global__ void pool_sum_kernel(const float* __restrict__ h,
                                const int* __restrict__ batch,
                                float* __restrict__ pooled,
                                float* __restrict__ counts)
{
    long long t = (long long)blockIdx.x * blockDim.x + threadIdx.x;
    if (t >= (long long)N_NODES * (HID / 4)) return;
    int i = (int)(t >> 6);            // node (HID/4 = 64 chunks per node)
    int c = (int)(t & 63) * 4;
    int g = batch[i];
    float4 v = *reinterpret_cast<const float4*>(h + (long long)i * HID + c);
    float* out = pooled + (long long)g * HID + c;
    atomicAdd(out + 0, v.x);
    atomicAdd(out + 1, v.y);
    atomicAdd(out + 2, v.z);
    atomicAdd(out + 3, v.w);
    if ((t & 63) == 0) atomicAdd(counts + g, 1.0f);
}

// ---------------------------------------------------------------------------
// out[g,c] = (pooled[g,:]/max(counts[g],1)) @ W_lin[:,c] + b_lin[c]
// ---------------------------------------------------------------------------
__global__ void final_kernel(const float* __restrict__ pooled,
                             const float* __restrict__ counts,
                             const float* __restrict__ W_lin,
                             const float* __restrict__ b_lin,
                             float* __restrict__ out)
{
    __shared__ float v[HID];
    int g = blockIdx.x;
    int t = threadIdx.x;  // 256
    float cnt = fmaxf(counts[g], 1.0f);
    v[t] = pooled[(long long)g * HID + t] / cnt;
    __syncthreads();
    if (t < N_CLASSES) {
        float s = b_lin[t];
        for (int k = 0; k < HID; ++k)
            s += v[k] * W_lin[k * N_CLASSES + t];
        out[g * N_CLASSES + t] = s;
    }
}

extern "C" void kernel_launch(void* const* d_in, const int* in_sizes, int n_in,
                              void* d_out, int out_size, void* d_ws, size_t ws_size,
                              hipStream_t stream)
{
    const float* x     = (const float*)d_in[0];
    const int*   ei    = (const int*)d_in[1];
    const int*   batch = (const int*)d_in[2];
    const float* W1r = (const float*)d_in[3];
    const float* W1n = (const float*)d_in[4];
    const float* b1  = (const float*)d_in[5];
    const float* W2r = (const float*)d_in[6];
    const float* W2n = (const float*)d_in[7];
    const float* b2  = (const float*)d_in[8];
    const float* W3r = (const float*)d_in[9];
    const float* W3n = (const float*)d_in[10];
    const float* b3  = (const float*)d_in[11];
    const float* Wl  = (const float*)d_in[12];
    const float* bl  = (const float*)d_in[13];
    float* out = (float*)d_out;

    const int* src = ei;            // edge_index[0,:]
    const int* dst = ei + N_EDGES;  // edge_index[1,:]

    const size_t NH = (size_t)N_NODES * HID;
    float* agg    = (float*)d_ws;        // N x HID (layer1 uses first N x 128)
    float* h1     = agg + NH;            // N x HID
    float* h2     = h1 + NH;             // N x HID
    float* pooled = h2 + NH;             // G x HID
    float* counts = pooled + (size_t)N_GRAPHS * HID;  // G

    dim3 gemm_grid((N_NODES + 63) / 64, HID / 64);

    // ---- layer 1 (K = 128, relu) ----
    hipMemsetAsync(agg, 0, (size_t)N_NODES * IN_CH * sizeof(float), stream);
    {
        long long total = (long long)N_EDGES * (IN_CH / 4);
        int blocks = (int)((total + 255) / 256);
        scatter_add_kernel<<<blocks, 256, 0, stream>>>(x, src, dst, agg, IN_CH, IN_CH / 4, total);
    }
    gconv_gemm_kernel<1><<<gemm_grid, 256, 0, stream>>>(x, agg, W1r, W1n, b1, h1,
                                                        N_NODES, IN_CH, HID);

    // ---- layer 2 (K = 256, relu) ----
    hipMemsetAsync(agg, 0, NH * sizeof(float), stream);
    {
        long long total = (long long)N_EDGES * (HID / 4);
        int blocks = (int)((total + 255) / 256);
        scatter_add_kernel<<<blocks, 256, 0, stream>>>(h1, src, dst, agg, HID, HID / 4, total);
    }
    gconv_gemm_kernel<1><<<gemm_grid, 256, 0, stream>>>(h1, agg, W2r, W2n, b2, h2,
                                                        N_NODES, HID, HID);

    // ---- layer 3 (K = 256, no relu) ----
    hipMemsetAsync(agg, 0, NH * sizeof(float), stream);
    {
        long long total = (long long)N_EDGES * (HID / 4);
        int blocks = (int)((total + 255) / 256);
        scatter_add_kernel<<<blocks, 256, 0, stream>>>(h2, src, dst, agg, HID, HID / 4, total);
    }
    gconv_gemm_kernel<0><<<gemm_grid, 256, 0, stream>>>(h2, agg, W3r, W3n, b3, h1,
                                                        N_NODES, HID, HID);

    // ---- global mean pool + classifier ----
    hipMemsetAsync(pooled, 0, ((size_t)N_GRAPHS * HID + N_GRAPHS) * sizeof(float), stream);
    {
        long long total = (long long)N_NODES * (HID / 4);
        int blocks = (int)((total + 255) / 256);
        pool_sum_kernel<<<blocks, 256, 0, stream>>>(h1, batch, pooled, counts);
    }
    final_kernel<<<N_GRAPHS, HID, 0, stream>>>(pooled, counts, Wl, bl, out);
}

// Round 2
// 1121.162 us; speedup vs baseline: 6.8354x; 6.8354x over previous
//
#include <hip/hip_runtime.h>

#define N_NODES 50000
#define N_EDGES 800000
#define IN_CH 128
#define HID 256
#define N_GRAPHS 64
#define N_CLASSES 10

// ===========================================================================
// CSR build (once per launch, reused by all 3 layers)
// ===========================================================================
__global__ void hist_kernel(const int* __restrict__ dst, int* __restrict__ deg)
{
    int e = blockIdx.x * blockDim.x + threadIdx.x;
    if (e < N_EDGES) atomicAdd(&deg[dst[e]], 1);
}

// single-block exclusive scan of deg[0..N) -> row_start[0..N], also copies to cursor
__global__ void __launch_bounds__(1024) scan_kernel(const int* __restrict__ deg,
                                                    int* __restrict__ row_start,
                                                    int* __restrict__ cursor)
{
    __shared__ int buf[1024];
    __shared__ int carry_s;
    int t = threadIdx.x;
    if (t == 0) carry_s = 0;
    __syncthreads();
    for (int base = 0; base < N_NODES; base += 1024) {
        int i = base + t;
        int v = (i < N_NODES) ? deg[i] : 0;
        buf[t] = v;
        __syncthreads();
        #pragma unroll
        for (int off = 1; off < 1024; off <<= 1) {
            int add = (t >= off) ? buf[t - off] : 0;
            __syncthreads();
            buf[t] += add;
            __syncthreads();
        }
        int excl = buf[t] - v;
        int carry = carry_s;
        if (i < N_NODES) {
            int rs = carry + excl;
            row_start[i] = rs;
            cursor[i] = rs;
        }
        __syncthreads();
        if (t == 1023) carry_s = carry + buf[1023];
        __syncthreads();
    }
    if (t == 0) row_start[N_NODES] = carry_s;
}

__global__ void fill_kernel(const int* __restrict__ src, const int* __restrict__ dst,
                            int* __restrict__ cursor, int* __restrict__ esrc)
{
    int e = blockIdx.x * blockDim.x + threadIdx.x;
    if (e < N_EDGES) {
        int d = dst[e];
        int pos = atomicAdd(&cursor[d], 1);
        esrc[pos] = src[e];
    }
}

// ===========================================================================
// agg[i,:] = sum_{j in in-neighbors(i)} feat[j,:]   via CSR — no atomics.
// D/4 threads per node (float4 each); D=256 -> one wave per node.
// ===========================================================================
template<int D>
__global__ void __launch_bounds__(256)
gather_kernel(const float* __restrict__ feat,
              const int* __restrict__ row_start,
              const int* __restrict__ esrc,
              float* __restrict__ agg)
{
    constexpr int GS = D / 4;        // threads per node
    constexpr int NPB = 256 / GS;    // nodes per block
    int node = blockIdx.x * NPB + threadIdx.x / GS;
    int lane = threadIdx.x % GS;
    if (node >= N_NODES) return;
    int s = row_start[node];
    int e = row_start[node + 1];
    float4 acc = make_float4(0.f, 0.f, 0.f, 0.f);
    int j = s;
    for (; j + 1 < e; j += 2) {
        int s0 = esrc[j];
        int s1 = esrc[j + 1];
        float4 v0 = *reinterpret_cast<const float4*>(feat + (long long)s0 * D + lane * 4);
        float4 v1 = *reinterpret_cast<const float4*>(feat + (long long)s1 * D + lane * 4);
        acc.x += v0.x; acc.y += v0.y; acc.z += v0.z; acc.w += v0.w;
        acc.x += v1.x; acc.y += v1.y; acc.z += v1.z; acc.w += v1.w;
    }
    if (j < e) {
        int s0 = esrc[j];
        float4 v0 = *reinterpret_cast<const float4*>(feat + (long long)s0 * D + lane * 4);
        acc.x += v0.x; acc.y += v0.y; acc.z += v0.z; acc.w += v0.w;
    }
    *reinterpret_cast<float4*>(agg + (long long)node * D + lane * 4) = acc;
}

// ===========================================================================
// C[i,j] = act( A1[i,:]@B1[:,j] + A2[i,:]@B2[:,j] + bias[j] )
// 64x64 tile per 256-thread block, 4x4 outputs per thread, BK=16.
// ===========================================================================
template<int RELU>
__global__ void __launch_bounds__(256)
gconv_gemm_kernel(const float* __restrict__ A1, const float* __restrict__ A2,
                  const float* __restrict__ B1, const float* __restrict__ B2,
                  const float* __restrict__ bias,
                  float* __restrict__ C,
                  int M, int K, int Ncols)
{
    __shared__ float As[16][68];
    __shared__ float Bs[16][64];

    const int tid = threadIdx.x;
    const int bm = blockIdx.x * 64;
    const int bn = blockIdx.y * 64;
    const int ty = tid >> 4;
    const int tx = tid & 15;

    float acc[4][4] = {};

    for (int mat = 0; mat < 2; ++mat) {
        const float* __restrict__ A = mat ? A2 : A1;
        const float* __restrict__ B = mat ? B2 : B1;
        for (int k0 = 0; k0 < K; k0 += 16) {
            {
                int m  = tid >> 2;
                int k4 = (tid & 3) * 4;
                int row = bm + m;
                float4 v = make_float4(0.f, 0.f, 0.f, 0.f);
                if (row < M)
                    v = *reinterpret_cast<const float4*>(A + (long long)row * K + k0 + k4);
                As[k4 + 0][m] = v.x;
                As[k4 + 1][m] = v.y;
                As[k4 + 2][m] = v.z;
                As[k4 + 3][m] = v.w;
            }
            {
                int k  = tid >> 4;
                int n4 = (tid & 15) * 4;
                float4 v = *reinterpret_cast<const float4*>(B + (long long)(k0 + k) * Ncols + bn + n4);
                *reinterpret_cast<float4*>(&Bs[k][n4]) = v;
            }
            __syncthreads();
            #pragma unroll
            for (int kk = 0; kk < 16; ++kk) {
                float4 a = *reinterpret_cast<const float4*>(&As[kk][ty * 4]);
                float4 b = *reinterpret_cast<const float4*>(&Bs[kk][tx * 4]);
                acc[0][0] += a.x * b.x; acc[0][1] += a.x * b.y; acc[0][2] += a.x * b.z; acc[0][3] += a.x * b.w;
                acc[1][0] += a.y * b.x; acc[1][1] += a.y * b.y; acc[1][2] += a.y * b.z; acc[1][3] += a.y * b.w;
                acc[2][0] += a.z * b.x; acc[2][1] += a.z * b.y; acc[2][2] += a.z * b.z; acc[2][3] += a.z * b.w;
                acc[3][0] += a.w * b.x; acc[3][1] += a.w * b.y; acc[3][2] += a.w * b.z; acc[3][3] += a.w * b.w;
            }
            __syncthreads();
        }
    }

    #pragma unroll
    for (int i = 0; i < 4; ++i) {
        int row = bm + ty * 4 + i;
        if (row >= M) continue;
        #pragma unroll
        for (int j = 0; j < 4; ++j) {
            int col = bn + tx * 4 + j;
            float v = acc[i][j] + bias[col];
            if (RELU) v = fmaxf(v, 0.f);
            C[(long long)row * Ncols + col] = v;
        }
    }
}

// ===========================================================================
// Pooling: batch is sorted -> binary-search graph boundaries, then
// one block per graph sums its contiguous row range. No atomics.
// ===========================================================================
__global__ void graph_bounds_kernel(const int* __restrict__ batch, int* __restrict__ gstart)
{
    int g = blockIdx.x * blockDim.x + threadIdx.x;
    if (g > N_GRAPHS) return;
    int lo = 0, hi = N_NODES;
    while (lo < hi) {
        int mid = (lo + hi) >> 1;
        if (batch[mid] < g) lo = mid + 1; else hi = mid;
    }
    gstart[g] = lo;
}

__global__ void pool_kernel(const float* __restrict__ h, const int* __restrict__ gstart,
                            float* __restrict__ pooled)
{
    int g = blockIdx.x;
    int t = threadIdx.x;  // 256 = HID
    int s = gstart[g], e = gstart[g + 1];
    float acc = 0.f;
    for (int i = s; i < e; ++i)
        acc += h[(long long)i * HID + t];
    float cnt = fmaxf((float)(e - s), 1.0f);
    pooled[g * HID + t] = acc / cnt;
}

__global__ void final_kernel(const float* __restrict__ pooled,
                             const float* __restrict__ W_lin,
                             const float* __restrict__ b_lin,
                             float* __restrict__ out)
{
    __shared__ float v[HID];
    int g = blockIdx.x;
    int t = threadIdx.x;
    v[t] = pooled[g * HID + t];
    __syncthreads();
    if (t < N_CLASSES) {
        float s = b_lin[t];
        for (int k = 0; k < HID; ++k)
            s += v[k] * W_lin[k * N_CLASSES + t];
        out[g * N_CLASSES + t] = s;
    }
}

extern "C" void kernel_launch(void* const* d_in, const int* in_sizes, int n_in,
                              void* d_out, int out_size, void* d_ws, size_t ws_size,
                              hipStream_t stream)
{
    const float* x     = (const float*)d_in[0];
    const int*   ei    = (const int*)d_in[1];
    const int*   batch = (const int*)d_in[2];
    const float* W1r = (const float*)d_in[3];
    const float* W1n = (const float*)d_in[4];
    const float* b1  = (const float*)d_in[5];
    const float* W2r = (const float*)d_in[6];
    const float* W2n = (const float*)d_in[7];
    const float* b2  = (const float*)d_in[8];
    const float* W3r = (const float*)d_in[9];
    const float* W3n = (const float*)d_in[10];
    const float* b3  = (const float*)d_in[11];
    const float* Wl  = (const float*)d_in[12];
    const float* bl  = (const float*)d_in[13];
    float* out = (float*)d_out;

    const int* src = ei;
    const int* dst = ei + N_EDGES;

    const size_t NH = (size_t)N_NODES * HID;
    float* agg    = (float*)d_ws;                       // N x 256
    float* h1     = agg + NH;                           // N x 256
    float* h2     = h1 + NH;                            // N x 256
    float* pooled = h2 + NH;                            // G x 256
    int*   deg      = (int*)(pooled + (size_t)N_GRAPHS * HID);
    int*   row_start = deg + N_NODES;                   // N+1
    int*   cursor    = row_start + N_NODES + 1;         // N
    int*   esrc      = cursor + N_NODES;                // E
    int*   gstart    = esrc + N_EDGES;                  // G+1

    const int EB = (N_EDGES + 255) / 256;

    // ---- CSR build ----
    hipMemsetAsync(deg, 0, N_NODES * sizeof(int), stream);
    hist_kernel<<<EB, 256, 0, stream>>>(dst, deg);
    scan_kernel<<<1, 1024, 0, stream>>>(deg, row_start, cursor);
    fill_kernel<<<EB, 256, 0, stream>>>(src, dst, cursor, esrc);

    dim3 gemm_grid((N_NODES + 63) / 64, HID / 64);

    // ---- layer 1 (K = 128, relu) ----
    gather_kernel<IN_CH><<<(N_NODES * (IN_CH / 4) + 255) / 256, 256, 0, stream>>>(x, row_start, esrc, agg);
    gconv_gemm_kernel<1><<<gemm_grid, 256, 0, stream>>>(x, agg, W1r, W1n, b1, h1,
                                                        N_NODES, IN_CH, HID);

    // ---- layer 2 (K = 256, relu) ----
    gather_kernel<HID><<<(N_NODES * (HID / 4) + 255) / 256, 256, 0, stream>>>(h1, row_start, esrc, agg);
    gconv_gemm_kernel<1><<<gemm_grid, 256, 0, stream>>>(h1, agg, W2r, W2n, b2, h2,
                                                        N_NODES, HID, HID);

    // ---- layer 3 (K = 256, no relu) ----
    gather_kernel<HID><<<(N_NODES * (HID / 4) + 255) / 256, 256, 0, stream>>>(h2, row_start, esrc, agg);
    gconv_gemm_kernel<0><<<gemm_grid, 256, 0, stream>>>(h2, agg, W3r, W3n, b3, h1,
                                                        N_NODES, HID, HID);

    // ---- global mean pool + classifier ----
    graph_bounds_kernel<<<1, 128, 0, stream>>>(batch, gstart);
    pool_kernel<<<N_GRAPHS, HID, 0, stream>>>(h1, gstart, pooled);
    final_kernel<<<N_GRAPHS, HID, 0, stream>>>(pooled, Wl, bl, out);
}

// Round 3
// 516.757 us; speedup vs baseline: 14.8301x; 2.1696x over previous
//
#include <hip/hip_runtime.h>
#include <stdint.h>

#define N_NODES 50000
#define N_EDGES 800000
#define IN_CH 128
#define HID 256
#define N_GRAPHS 64
#define N_CLASSES 10

typedef unsigned short u16;
typedef __attribute__((ext_vector_type(8))) short short8;
typedef __attribute__((ext_vector_type(4))) float f32x4;

__device__ __forceinline__ float bf2f(uint32_t u) {
    union { uint32_t i; float f; } v; v.i = u << 16; return v.f;
}
__device__ __forceinline__ uint32_t f2bf(float f) {
    union { float f; uint32_t i; } v; v.f = f;
    return (v.i + 0x7FFFu + ((v.i >> 16) & 1u)) >> 16;   // RNE
}

// ===========================================================================
// CSR build
// ===========================================================================
__global__ void hist_kernel(const int* __restrict__ dst, int* __restrict__ deg)
{
    int e = blockIdx.x * blockDim.x + threadIdx.x;
    if (e < N_EDGES) atomicAdd(&deg[dst[e]], 1);
}

// single-block scan: each thread owns a contiguous segment (~49 nodes)
__global__ void __launch_bounds__(1024) scan_kernel(const int* __restrict__ deg,
                                                    int* __restrict__ row_start,
                                                    int* __restrict__ cursor)
{
    __shared__ int buf[1024];
    const int SEG = (N_NODES + 1023) / 1024;
    int t = threadIdx.x;
    int beg = t * SEG;
    int end = min(beg + SEG, N_NODES);
    int s = 0;
    for (int i = beg; i < end; ++i) s += deg[i];
    buf[t] = s;
    __syncthreads();
    #pragma unroll
    for (int off = 1; off < 1024; off <<= 1) {
        int v = (t >= off) ? buf[t - off] : 0;
        __syncthreads();
        buf[t] += v;
        __syncthreads();
    }
    int run = buf[t] - s;   // exclusive prefix
    for (int i = beg; i < end; ++i) {
        row_start[i] = run; cursor[i] = run;
        run += deg[i];
    }
    if (t == 1023) row_start[N_NODES] = run;
}

__global__ void fill_kernel(const int* __restrict__ src, const int* __restrict__ dst,
                            int* __restrict__ cursor, int* __restrict__ esrc)
{
    int e = blockIdx.x * blockDim.x + threadIdx.x;
    if (e < N_EDGES) {
        int pos = atomicAdd(&cursor[dst[e]], 1);
        esrc[pos] = src[e];
    }
}

// ===========================================================================
// fp32 -> bf16 conversions
// ===========================================================================
__global__ void cvt_x_kernel(const float* __restrict__ x, u16* __restrict__ xb)
{
    int id = blockIdx.x * blockDim.x + threadIdx.x;   // one per 8 elements
    if (id >= N_NODES * (IN_CH / 8)) return;
    const float4 a = *reinterpret_cast<const float4*>(x + (size_t)id * 8);
    const float4 b = *reinterpret_cast<const float4*>(x + (size_t)id * 8 + 4);
    uint4 o;
    o.x = f2bf(a.x) | (f2bf(a.y) << 16);
    o.y = f2bf(a.z) | (f2bf(a.w) << 16);
    o.z = f2bf(b.x) | (f2bf(b.y) << 16);
    o.w = f2bf(b.z) | (f2bf(b.w) << 16);
    *reinterpret_cast<uint4*>(xb + (size_t)id * 8) = o;
}

// transpose-convert up to 4 weights [K,256] fp32 -> [256,K] bf16
__global__ void twt_kernel(const float* W0, const float* W1, const float* W2, const float* W3,
                           u16* o0, u16* o1, u16* o2, u16* o3, int K, int nmat)
{
    int id = blockIdx.x * blockDim.x + threadIdx.x;
    int per = K * HID;
    int m = id / per;
    if (m >= nmat) return;
    int r = id % per;
    int k = r / HID, n = r % HID;
    const float* W = (m == 0) ? W0 : (m == 1) ? W1 : (m == 2) ? W2 : W3;
    u16* O = (m == 0) ? o0 : (m == 1) ? o1 : (m == 2) ? o2 : o3;
    O[(size_t)n * K + k] = (u16)f2bf(W[r]);
}

// ===========================================================================
// agg[i,:] = sum_{j in in(i)} feat[j,:]  — bf16 in/out, fp32 accumulate
// ===========================================================================
template<int D>
__global__ void __launch_bounds__(256)
gather_bf(const u16* __restrict__ feat, const int* __restrict__ row_start,
          const int* __restrict__ esrc, u16* __restrict__ agg)
{
    constexpr int GS = D / 8;        // threads per node (16B each)
    constexpr int NPB = 256 / GS;
    int node = blockIdx.x * NPB + threadIdx.x / GS;
    int lane = threadIdx.x % GS;
    if (node >= N_NODES) return;
    const int s = row_start[node], e = row_start[node + 1];
    float acc[8] = {0.f, 0.f, 0.f, 0.f, 0.f, 0.f, 0.f, 0.f};
    const u16* fp = feat + lane * 8;
    int j = s;
    for (; j + 1 < e; j += 2) {
        int s0 = esrc[j], s1 = esrc[j + 1];
        uint4 v0 = *reinterpret_cast<const uint4*>(fp + (size_t)s0 * D);
        uint4 v1 = *reinterpret_cast<const uint4*>(fp + (size_t)s1 * D);
        acc[0] += bf2f(v0.x & 0xFFFF) + bf2f(v1.x & 0xFFFF);
        acc[1] += bf2f(v0.x >> 16)    + bf2f(v1.x >> 16);
        acc[2] += bf2f(v0.y & 0xFFFF) + bf2f(v1.y & 0xFFFF);
        acc[3] += bf2f(v0.y >> 16)    + bf2f(v1.y >> 16);
        acc[4] += bf2f(v0.z & 0xFFFF) + bf2f(v1.z & 0xFFFF);
        acc[5] += bf2f(v0.z >> 16)    + bf2f(v1.z >> 16);
        acc[6] += bf2f(v0.w & 0xFFFF) + bf2f(v1.w & 0xFFFF);
        acc[7] += bf2f(v0.w >> 16)    + bf2f(v1.w >> 16);
    }
    if (j < e) {
        uint4 v0 = *reinterpret_cast<const uint4*>(fp + (size_t)esrc[j] * D);
        acc[0] += bf2f(v0.x & 0xFFFF); acc[1] += bf2f(v0.x >> 16);
        acc[2] += bf2f(v0.y & 0xFFFF); acc[3] += bf2f(v0.y >> 16);
        acc[4] += bf2f(v0.z & 0xFFFF); acc[5] += bf2f(v0.z >> 16);
        acc[6] += bf2f(v0.w & 0xFFFF); acc[7] += bf2f(v0.w >> 16);
    }
    uint4 o;
    o.x = f2bf(acc[0]) | (f2bf(acc[1]) << 16);
    o.y = f2bf(acc[2]) | (f2bf(acc[3]) << 16);
    o.z = f2bf(acc[4]) | (f2bf(acc[5]) << 16);
    o.w = f2bf(acc[6]) | (f2bf(acc[7]) << 16);
    *reinterpret_cast<uint4*>(agg + (size_t)node * D + lane * 8) = o;
}

// ===========================================================================
// C[m,n] = act( A1@W1 + A2@W2 + bias )   — bf16 MFMA, fp32 acc, bf16 out
// A*: [M,K] bf16 row-major.  B*t: [256,K] bf16 (transposed weights).
// 128x128 tile, 4 waves (2x2), each wave 64x64 = 4x4 fragments of 16x16x32.
// LDS rows padded to 40 halves (80B) -> conflict-free ds_read_b128.
// ===========================================================================
template<int RELU>
__global__ void __launch_bounds__(256)
mfma_gemm(const u16* __restrict__ A1, const u16* __restrict__ A2,
          const u16* __restrict__ B1t, const u16* __restrict__ B2t,
          const float* __restrict__ bias,
          u16* __restrict__ C,
          int M, int K)
{
    __shared__ __align__(16) u16 As[128][40];
    __shared__ __align__(16) u16 Bs[128][40];

    const int tid = threadIdx.x;
    const int bm = blockIdx.x * 128;
    const int bn = blockIdx.y * 128;
    const int w  = tid >> 6;
    const int wm = (w >> 1) * 64;
    const int wn = (w & 1) * 64;
    const int l  = tid & 63;
    const int lr = l & 15;          // row within 16x16 fragment
    const int kb = (l >> 4) * 8;    // k base within K=32 slice

    f32x4 acc[4][4];
    #pragma unroll
    for (int i = 0; i < 4; ++i)
        #pragma unroll
        for (int j = 0; j < 4; ++j)
            acc[i][j] = (f32x4){0.f, 0.f, 0.f, 0.f};

    const int row_s = tid >> 2;         // staging: 64 rows per iter
    const int c8    = (tid & 3) * 8;

    for (int mat = 0; mat < 2; ++mat) {
        const u16* __restrict__ Ag = mat ? A2 : A1;
        const u16* __restrict__ Bg = mat ? B2t : B1t;
        for (int k0 = 0; k0 < K; k0 += 32) {
            #pragma unroll
            for (int it = 0; it < 2; ++it) {
                int row = row_s + it * 64;
                uint4 va = make_uint4(0u, 0u, 0u, 0u);
                int gr = bm + row;
                if (gr < M)
                    va = *reinterpret_cast<const uint4*>(Ag + (size_t)gr * K + k0 + c8);
                *reinterpret_cast<uint4*>(&As[row][c8]) = va;
                uint4 vb = *reinterpret_cast<const uint4*>(Bg + (size_t)(bn + row) * K + k0 + c8);
                *reinterpret_cast<uint4*>(&Bs[row][c8]) = vb;
            }
            __syncthreads();
            short8 af[4], bfr[4];
            #pragma unroll
            for (int f = 0; f < 4; ++f) {
                af[f]  = *reinterpret_cast<const short8*>(&As[wm + f * 16 + lr][kb]);
                bfr[f] = *reinterpret_cast<const short8*>(&Bs[wn + f * 16 + lr][kb]);
            }
            #pragma unroll
            for (int fm = 0; fm < 4; ++fm)
                #pragma unroll
                for (int fn = 0; fn < 4; ++fn)
                    acc[fm][fn] = __builtin_amdgcn_mfma_f32_16x16x32_bf16(
                        af[fm], bfr[fn], acc[fm][fn], 0, 0, 0);
            __syncthreads();
        }
    }

    // epilogue: C/D layout col=lane&15, row=(lane>>4)*4+reg
    const int r4 = (l >> 4) * 4;
    #pragma unroll
    for (int fm = 0; fm < 4; ++fm) {
        #pragma unroll
        for (int r = 0; r < 4; ++r) {
            int row = bm + wm + fm * 16 + r4 + r;
            if (row >= M) continue;
            #pragma unroll
            for (int fn = 0; fn < 4; ++fn) {
                int col = bn + wn + fn * 16 + lr;
                float v = acc[fm][fn][r] + bias[col];
                if (RELU) v = fmaxf(v, 0.f);
                C[(size_t)row * HID + col] = (u16)f2bf(v);
            }
        }
    }
}

// ===========================================================================
// Pooling (batch sorted): boundaries + two-stage mean
// ===========================================================================
__global__ void graph_bounds_kernel(const int* __restrict__ batch, int* __restrict__ gstart)
{
    int g = blockIdx.x * blockDim.x + threadIdx.x;
    if (g > N_GRAPHS) return;
    int lo = 0, hi = N_NODES;
    while (lo < hi) {
        int mid = (lo + hi) >> 1;
        if (batch[mid] < g) lo = mid + 1; else hi = mid;
    }
    gstart[g] = lo;
}

__global__ void pool1_kernel(const u16* __restrict__ h, const int* __restrict__ gstart,
                             float* __restrict__ partial)
{
    int g = blockIdx.x >> 3;
    int c = blockIdx.x & 7;
    int t = threadIdx.x;      // 256
    int s = gstart[g], e = gstart[g + 1];
    int cnt = e - s;
    int a = s + (int)(((long long)cnt * c) >> 3);
    int b = s + (int)(((long long)cnt * (c + 1)) >> 3);
    float acc = 0.f;
    for (int i = a; i < b; ++i)
        acc += bf2f(h[(size_t)i * HID + t]);
    partial[(size_t)blockIdx.x * HID + t] = acc;
}

__global__ void pool2_kernel(const float* __restrict__ partial, const int* __restrict__ gstart,
                             float* __restrict__ pooled)
{
    int g = blockIdx.x;
    int t = threadIdx.x;
    float acc = 0.f;
    #pragma unroll
    for (int c = 0; c < 8; ++c)
        acc += partial[(size_t)(g * 8 + c) * HID + t];
    float cnt = fmaxf((float)(gstart[g + 1] - gstart[g]), 1.f);
    pooled[g * HID + t] = acc / cnt;
}

__global__ void final_kernel(const float* __restrict__ pooled,
                             const float* __restrict__ W_lin,
                             const float* __restrict__ b_lin,
                             float* __restrict__ out)
{
    __shared__ float v[HID];
    int g = blockIdx.x;
    int t = threadIdx.x;
    v[t] = pooled[g * HID + t];
    __syncthreads();
    if (t < N_CLASSES) {
        float s = b_lin[t];
        for (int k = 0; k < HID; ++k)
            s += v[k] * W_lin[k * N_CLASSES + t];
        out[g * N_CLASSES + t] = s;
    }
}

// ===========================================================================
extern "C" void kernel_launch(void* const* d_in, const int* in_sizes, int n_in,
                              void* d_out, int out_size, void* d_ws, size_t ws_size,
                              hipStream_t stream)
{
    const float* x     = (const float*)d_in[0];
    const int*   ei    = (const int*)d_in[1];
    const int*   batch = (const int*)d_in[2];
    const float* W1r = (const float*)d_in[3];
    const float* W1n = (const float*)d_in[4];
    const float* b1  = (const float*)d_in[5];
    const float* W2r = (const float*)d_in[6];
    const float* W2n = (const float*)d_in[7];
    const float* b2  = (const float*)d_in[8];
    const float* W3r = (const float*)d_in[9];
    const float* W3n = (const float*)d_in[10];
    const float* b3  = (const float*)d_in[11];
    const float* Wl  = (const float*)d_in[12];
    const float* bl  = (const float*)d_in[13];
    float* out = (float*)d_out;

    const int* src = ei;
    const int* dst = ei + N_EDGES;

    // ---- workspace layout (256B-aligned chunks) ----
    char* base = (char*)d_ws;
    size_t off = 0;
    auto alloc = [&](size_t bytes) { char* p = base + off; off += (bytes + 255) & ~(size_t)255; return p; };
    u16* x_bf = (u16*)alloc((size_t)N_NODES * IN_CH * 2);
    u16* hA   = (u16*)alloc((size_t)N_NODES * HID * 2);
    u16* hB   = (u16*)alloc((size_t)N_NODES * HID * 2);
    u16* agg  = (u16*)alloc((size_t)N_NODES * HID * 2);
    u16* wt1r = (u16*)alloc((size_t)HID * IN_CH * 2);
    u16* wt1n = (u16*)alloc((size_t)HID * IN_CH * 2);
    u16* wt2r = (u16*)alloc((size_t)HID * HID * 2);
    u16* wt2n = (u16*)alloc((size_t)HID * HID * 2);
    u16* wt3r = (u16*)alloc((size_t)HID * HID * 2);
    u16* wt3n = (u16*)alloc((size_t)HID * HID * 2);
    float* partial = (float*)alloc((size_t)N_GRAPHS * 8 * HID * 4);
    float* pooled  = (float*)alloc((size_t)N_GRAPHS * HID * 4);
    int* deg       = (int*)alloc((size_t)N_NODES * 4);
    int* row_start = (int*)alloc((size_t)(N_NODES + 1) * 4);
    int* cursor    = (int*)alloc((size_t)N_NODES * 4);
    int* esrc      = (int*)alloc((size_t)N_EDGES * 4);
    int* gstart    = (int*)alloc((size_t)(N_GRAPHS + 1) * 4);

    const int EB = (N_EDGES + 255) / 256;

    // ---- CSR build ----
    hipMemsetAsync(deg, 0, N_NODES * sizeof(int), stream);
    hist_kernel<<<EB, 256, 0, stream>>>(dst, deg);
    scan_kernel<<<1, 1024, 0, stream>>>(deg, row_start, cursor);
    fill_kernel<<<EB, 256, 0, stream>>>(src, dst, cursor, esrc);

    // ---- conversions ----
    cvt_x_kernel<<<(N_NODES * (IN_CH / 8) + 255) / 256, 256, 0, stream>>>(x, x_bf);
    twt_kernel<<<(2 * IN_CH * HID + 255) / 256, 256, 0, stream>>>(
        W1r, W1n, nullptr, nullptr, wt1r, wt1n, nullptr, nullptr, IN_CH, 2);
    twt_kernel<<<(4 * HID * HID + 255) / 256, 256, 0, stream>>>(
        W2r, W2n, W3r, W3n, wt2r, wt2n, wt3r, wt3n, HID, 4);

    dim3 gemm_grid((N_NODES + 127) / 128, HID / 128);

    // ---- layer 1 (K=128, relu) ----
    gather_bf<IN_CH><<<(N_NODES * (IN_CH / 8) / 256) + 1, 256, 0, stream>>>(x_bf, row_start, esrc, agg);
    mfma_gemm<1><<<gemm_grid, 256, 0, stream>>>(x_bf, agg, wt1r, wt1n, b1, hA, N_NODES, IN_CH);

    // ---- layer 2 (K=256, relu) ----
    gather_bf<HID><<<(N_NODES * (HID / 8) / 256) + 1, 256, 0, stream>>>(hA, row_start, esrc, agg);
    mfma_gemm<1><<<gemm_grid, 256, 0, stream>>>(hA, agg, wt2r, wt2n, b2, hB, N_NODES, HID);

    // ---- layer 3 (K=256, no relu) ----
    gather_bf<HID><<<(N_NODES * (HID / 8) / 256) + 1, 256, 0, stream>>>(hB, row_start, esrc, agg);
    mfma_gemm<0><<<gemm_grid, 256, 0, stream>>>(hB, agg, wt3r, wt3n, b3, hA, N_NODES, HID);

    // ---- pool + classifier ----
    graph_bounds_kernel<<<1, 128, 0, stream>>>(batch, gstart);
    pool1_kernel<<<N_GRAPHS * 8, HID, 0, stream>>>(hA, gstart, partial);
    pool2_kernel<<<N_GRAPHS, HID, 0, stream>>>(partial, gstart, pooled);
    final_kernel<<<N_GRAPHS, HID, 0, stream>>>(pooled, Wl, bl, out);
}

// Round 4
// 415.482 us; speedup vs baseline: 18.4450x; 1.2438x over previous
//
#include <hip/hip_runtime.h>
#include <stdint.h>

#define N_NODES 50000
#define N_EDGES 800000
#define IN_CH 128
#define HID 256
#define N_GRAPHS 64
#define N_CLASSES 10

#define SCAN_BLOCKS ((N_NODES + 255) / 256)   // 196

typedef unsigned short u16;
typedef __attribute__((ext_vector_type(8))) short short8;
typedef __attribute__((ext_vector_type(4))) float f32x4;

__device__ __forceinline__ float bf2f(uint32_t u) {
    union { uint32_t i; float f; } v; v.i = u << 16; return v.f;
}
__device__ __forceinline__ uint32_t f2bf(float f) {
    union { float f; uint32_t i; } v; v.f = f;
    return (v.i + 0x7FFFu + ((v.i >> 16) & 1u)) >> 16;   // RNE
}

// ===========================================================================
// CSR build
// ===========================================================================
__global__ void hist_kernel(const int* __restrict__ dst, int* __restrict__ deg)
{
    int e = blockIdx.x * blockDim.x + threadIdx.x;
    if (e < N_EDGES) atomicAdd(&deg[dst[e]], 1);
}

// phase 1: per-block sums of deg (coalesced)
__global__ void __launch_bounds__(256) scan_p1(const int* __restrict__ deg, int* __restrict__ bsum)
{
    __shared__ int buf[256];
    int i = blockIdx.x * 256 + threadIdx.x;
    int v = (i < N_NODES) ? deg[i] : 0;
    buf[threadIdx.x] = v;
    __syncthreads();
    #pragma unroll
    for (int off = 128; off > 0; off >>= 1) {
        if (threadIdx.x < off) buf[threadIdx.x] += buf[threadIdx.x + off];
        __syncthreads();
    }
    if (threadIdx.x == 0) bsum[blockIdx.x] = buf[0];
}

// phase 2: single block scans the 196 block sums -> exclusive boff, total
__global__ void __launch_bounds__(256) scan_p2(const int* __restrict__ bsum,
                                               int* __restrict__ boff,
                                               int* __restrict__ row_start)
{
    __shared__ int buf[256];
    int t = threadIdx.x;
    int v = (t < SCAN_BLOCKS) ? bsum[t] : 0;
    buf[t] = v;
    __syncthreads();
    #pragma unroll
    for (int off = 1; off < 256; off <<= 1) {
        int a = (t >= off) ? buf[t - off] : 0;
        __syncthreads();
        buf[t] += a;
        __syncthreads();
    }
    if (t < SCAN_BLOCKS) boff[t] = buf[t] - v;          // exclusive
    if (t == 255) row_start[N_NODES] = buf[255];        // total == N_EDGES
}

// phase 3: per-block local exclusive scan + block offset -> row_start, cursor
__global__ void __launch_bounds__(256) scan_p3(const int* __restrict__ deg,
                                               const int* __restrict__ boff,
                                               int* __restrict__ row_start,
                                               int* __restrict__ cursor)
{
    __shared__ int buf[256];
    int t = threadIdx.x;
    int i = blockIdx.x * 256 + t;
    int v = (i < N_NODES) ? deg[i] : 0;
    buf[t] = v;
    __syncthreads();
    #pragma unroll
    for (int off = 1; off < 256; off <<= 1) {
        int a = (t >= off) ? buf[t - off] : 0;
        __syncthreads();
        buf[t] += a;
        __syncthreads();
    }
    if (i < N_NODES) {
        int rs = boff[blockIdx.x] + buf[t] - v;
        row_start[i] = rs;
        cursor[i] = rs;
    }
}

__global__ void fill_kernel(const int* __restrict__ src, const int* __restrict__ dst,
                            int* __restrict__ cursor, int* __restrict__ esrc)
{
    int e = blockIdx.x * blockDim.x + threadIdx.x;
    if (e < N_EDGES) {
        int pos = atomicAdd(&cursor[dst[e]], 1);
        esrc[pos] = src[e];
    }
}

// ===========================================================================
// fp32 -> bf16 conversions
// ===========================================================================
__global__ void cvt_x_kernel(const float* __restrict__ x, u16* __restrict__ xb)
{
    int id = blockIdx.x * blockDim.x + threadIdx.x;   // one per 8 elements
    if (id >= N_NODES * (IN_CH / 8)) return;
    const float4 a = *reinterpret_cast<const float4*>(x + (size_t)id * 8);
    const float4 b = *reinterpret_cast<const float4*>(x + (size_t)id * 8 + 4);
    uint4 o;
    o.x = f2bf(a.x) | (f2bf(a.y) << 16);
    o.y = f2bf(a.z) | (f2bf(a.w) << 16);
    o.z = f2bf(b.x) | (f2bf(b.y) << 16);
    o.w = f2bf(b.z) | (f2bf(b.w) << 16);
    *reinterpret_cast<uint4*>(xb + (size_t)id * 8) = o;
}

// transpose-convert up to 4 weights [K,256] fp32 -> [256,K] bf16
__global__ void twt_kernel(const float* W0, const float* W1, const float* W2, const float* W3,
                           u16* o0, u16* o1, u16* o2, u16* o3, int K, int nmat)
{
    int id = blockIdx.x * blockDim.x + threadIdx.x;
    int per = K * HID;
    int m = id / per;
    if (m >= nmat) return;
    int r = id % per;
    int k = r / HID, n = r % HID;
    const float* W = (m == 0) ? W0 : (m == 1) ? W1 : (m == 2) ? W2 : W3;
    u16* O = (m == 0) ? o0 : (m == 1) ? o1 : (m == 2) ? o2 : o3;
    O[(size_t)n * K + k] = (u16)f2bf(W[r]);
}

// ===========================================================================
// agg[i,:] = sum_{j in in(i)} feat[j,:]  — bf16 in/out, fp32 accumulate
// ===========================================================================
template<int D>
__global__ void __launch_bounds__(256)
gather_bf(const u16* __restrict__ feat, const int* __restrict__ row_start,
          const int* __restrict__ esrc, u16* __restrict__ agg)
{
    constexpr int GS = D / 8;        // threads per node (16B each)
    constexpr int NPB = 256 / GS;
    int node = blockIdx.x * NPB + threadIdx.x / GS;
    int lane = threadIdx.x % GS;
    if (node >= N_NODES) return;
    const int s = row_start[node], e = row_start[node + 1];
    float acc[8] = {0.f, 0.f, 0.f, 0.f, 0.f, 0.f, 0.f, 0.f};
    const u16* fp = feat + lane * 8;
    int j = s;
    for (; j + 1 < e; j += 2) {
        int s0 = esrc[j], s1 = esrc[j + 1];
        uint4 v0 = *reinterpret_cast<const uint4*>(fp + (size_t)s0 * D);
        uint4 v1 = *reinterpret_cast<const uint4*>(fp + (size_t)s1 * D);
        acc[0] += bf2f(v0.x & 0xFFFF) + bf2f(v1.x & 0xFFFF);
        acc[1] += bf2f(v0.x >> 16)    + bf2f(v1.x >> 16);
        acc[2] += bf2f(v0.y & 0xFFFF) + bf2f(v1.y & 0xFFFF);
        acc[3] += bf2f(v0.y >> 16)    + bf2f(v1.y >> 16);
        acc[4] += bf2f(v0.z & 0xFFFF) + bf2f(v1.z & 0xFFFF);
        acc[5] += bf2f(v0.z >> 16)    + bf2f(v1.z >> 16);
        acc[6] += bf2f(v0.w & 0xFFFF) + bf2f(v1.w & 0xFFFF);
        acc[7] += bf2f(v0.w >> 16)    + bf2f(v1.w >> 16);
    }
    if (j < e) {
        uint4 v0 = *reinterpret_cast<const uint4*>(fp + (size_t)esrc[j] * D);
        acc[0] += bf2f(v0.x & 0xFFFF); acc[1] += bf2f(v0.x >> 16);
        acc[2] += bf2f(v0.y & 0xFFFF); acc[3] += bf2f(v0.y >> 16);
        acc[4] += bf2f(v0.z & 0xFFFF); acc[5] += bf2f(v0.z >> 16);
        acc[6] += bf2f(v0.w & 0xFFFF); acc[7] += bf2f(v0.w >> 16);
    }
    uint4 o;
    o.x = f2bf(acc[0]) | (f2bf(acc[1]) << 16);
    o.y = f2bf(acc[2]) | (f2bf(acc[3]) << 16);
    o.z = f2bf(acc[4]) | (f2bf(acc[5]) << 16);
    o.w = f2bf(acc[6]) | (f2bf(acc[7]) << 16);
    *reinterpret_cast<uint4*>(agg + (size_t)node * D + lane * 8) = o;
}

// ===========================================================================
// C[m,n] = act( A1@W1 + A2@W2 + bias )   — bf16 MFMA, fp32 acc, bf16 out
// A*: [M,K] bf16 row-major.  B*t: [256,K] bf16 (transposed weights).
// 128x128 tile, 4 waves (2x2), each wave 64x64 = 4x4 fragments of 16x16x32.
// LDS rows padded to 40 halves (80B) -> conflict-free ds_read_b128.
// ===========================================================================
template<int RELU>
__global__ void __launch_bounds__(256)
mfma_gemm(const u16* __restrict__ A1, const u16* __restrict__ A2,
          const u16* __restrict__ B1t, const u16* __restrict__ B2t,
          const float* __restrict__ bias,
          u16* __restrict__ C,
          int M, int K)
{
    __shared__ __align__(16) u16 As[128][40];
    __shared__ __align__(16) u16 Bs[128][40];

    const int tid = threadIdx.x;
    const int bm = blockIdx.x * 128;
    const int bn = blockIdx.y * 128;
    const int w  = tid >> 6;
    const int wm = (w >> 1) * 64;
    const int wn = (w & 1) * 64;
    const int l  = tid & 63;
    const int lr = l & 15;          // row within 16x16 fragment
    const int kb = (l >> 4) * 8;    // k base within K=32 slice

    f32x4 acc[4][4];
    #pragma unroll
    for (int i = 0; i < 4; ++i)
        #pragma unroll
        for (int j = 0; j < 4; ++j)
            acc[i][j] = (f32x4){0.f, 0.f, 0.f, 0.f};

    const int row_s = tid >> 2;         // staging: 64 rows per iter
    const int c8    = (tid & 3) * 8;

    for (int mat = 0; mat < 2; ++mat) {
        const u16* __restrict__ Ag = mat ? A2 : A1;
        const u16* __restrict__ Bg = mat ? B2t : B1t;
        for (int k0 = 0; k0 < K; k0 += 32) {
            #pragma unroll
            for (int it = 0; it < 2; ++it) {
                int row = row_s + it * 64;
                uint4 va = make_uint4(0u, 0u, 0u, 0u);
                int gr = bm + row;
                if (gr < M)
                    va = *reinterpret_cast<const uint4*>(Ag + (size_t)gr * K + k0 + c8);
                *reinterpret_cast<uint4*>(&As[row][c8]) = va;
                uint4 vb = *reinterpret_cast<const uint4*>(Bg + (size_t)(bn + row) * K + k0 + c8);
                *reinterpret_cast<uint4*>(&Bs[row][c8]) = vb;
            }
            __syncthreads();
            short8 af[4], bfr[4];
            #pragma unroll
            for (int f = 0; f < 4; ++f) {
                af[f]  = *reinterpret_cast<const short8*>(&As[wm + f * 16 + lr][kb]);
                bfr[f] = *reinterpret_cast<const short8*>(&Bs[wn + f * 16 + lr][kb]);
            }
            #pragma unroll
            for (int fm = 0; fm < 4; ++fm)
                #pragma unroll
                for (int fn = 0; fn < 4; ++fn)
                    acc[fm][fn] = __builtin_amdgcn_mfma_f32_16x16x32_bf16(
                        af[fm], bfr[fn], acc[fm][fn], 0, 0, 0);
            __syncthreads();
        }
    }

    // epilogue: C/D layout col=lane&15, row=(lane>>4)*4+reg
    const int r4 = (l >> 4) * 4;
    #pragma unroll
    for (int fm = 0; fm < 4; ++fm) {
        #pragma unroll
        for (int r = 0; r < 4; ++r) {
            int row = bm + wm + fm * 16 + r4 + r;
            if (row >= M) continue;
            #pragma unroll
            for (int fn = 0; fn < 4; ++fn) {
                int col = bn + wn + fn * 16 + lr;
                float v = acc[fm][fn][r] + bias[col];
                if (RELU) v = fmaxf(v, 0.f);
                C[(size_t)row * HID + col] = (u16)f2bf(v);
            }
        }
    }
}

// ===========================================================================
// Pooling (batch sorted): boundaries + two-stage mean
// ===========================================================================
__global__ void graph_bounds_kernel(const int* __restrict__ batch, int* __restrict__ gstart)
{
    int g = blockIdx.x * blockDim.x + threadIdx.x;
    if (g > N_GRAPHS) return;
    int lo = 0, hi = N_NODES;
    while (lo < hi) {
        int mid = (lo + hi) >> 1;
        if (batch[mid] < g) lo = mid + 1; else hi = mid;
    }
    gstart[g] = lo;
}

__global__ void pool1_kernel(const u16* __restrict__ h, const int* __restrict__ gstart,
                             float* __restrict__ partial)
{
    int g = blockIdx.x >> 3;
    int c = blockIdx.x & 7;
    int t = threadIdx.x;      // 256
    int s = gstart[g], e = gstart[g + 1];
    int cnt = e - s;
    int a = s + (int)(((long long)cnt * c) >> 3);
    int b = s + (int)(((long long)cnt * (c + 1)) >> 3);
    float acc = 0.f;
    for (int i = a; i < b; ++i)
        acc += bf2f(h[(size_t)i * HID + t]);
    partial[(size_t)blockIdx.x * HID + t] = acc;
}

__global__ void pool2_kernel(const float* __restrict__ partial, const int* __restrict__ gstart,
                             float* __restrict__ pooled)
{
    int g = blockIdx.x;
    int t = threadIdx.x;
    float acc = 0.f;
    #pragma unroll
    for (int c = 0; c < 8; ++c)
        acc += partial[(size_t)(g * 8 + c) * HID + t];
    float cnt = fmaxf((float)(gstart[g + 1] - gstart[g]), 1.f);
    pooled[g * HID + t] = acc / cnt;
}

__global__ void final_kernel(const float* __restrict__ pooled,
                             const float* __restrict__ W_lin,
                             const float* __restrict__ b_lin,
                             float* __restrict__ out)
{
    __shared__ float v[HID];
    int g = blockIdx.x;
    int t = threadIdx.x;
    v[t] = pooled[g * HID + t];
    __syncthreads();
    if (t < N_CLASSES) {
        float s = b_lin[t];
        for (int k = 0; k < HID; ++k)
            s += v[k] * W_lin[k * N_CLASSES + t];
        out[g * N_CLASSES + t] = s;
    }
}

// ===========================================================================
extern "C" void kernel_launch(void* const* d_in, const int* in_sizes, int n_in,
                              void* d_out, int out_size, void* d_ws, size_t ws_size,
                              hipStream_t stream)
{
    const float* x     = (const float*)d_in[0];
    const int*   ei    = (const int*)d_in[1];
    const int*   batch = (const int*)d_in[2];
    const float* W1r = (const float*)d_in[3];
    const float* W1n = (const float*)d_in[4];
    const float* b1  = (const float*)d_in[5];
    const float* W2r = (const float*)d_in[6];
    const float* W2n = (const float*)d_in[7];
    const float* b2  = (const float*)d_in[8];
    const float* W3r = (const float*)d_in[9];
    const float* W3n = (const float*)d_in[10];
    const float* b3  = (const float*)d_in[11];
    const float* Wl  = (const float*)d_in[12];
    const float* bl  = (const float*)d_in[13];
    float* out = (float*)d_out;

    const int* src = ei;
    const int* dst = ei + N_EDGES;

    // ---- workspace layout (256B-aligned chunks) ----
    char* base = (char*)d_ws;
    size_t off = 0;
    auto alloc = [&](size_t bytes) { char* p = base + off; off += (bytes + 255) & ~(size_t)255; return p; };
    u16* x_bf = (u16*)alloc((size_t)N_NODES * IN_CH * 2);
    u16* hA   = (u16*)alloc((size_t)N_NODES * HID * 2);
    u16* hB   = (u16*)alloc((size_t)N_NODES * HID * 2);
    u16* agg  = (u16*)alloc((size_t)N_NODES * HID * 2);
    u16* wt1r = (u16*)alloc((size_t)HID * IN_CH * 2);
    u16* wt1n = (u16*)alloc((size_t)HID * IN_CH * 2);
    u16* wt2r = (u16*)alloc((size_t)HID * HID * 2);
    u16* wt2n = (u16*)alloc((size_t)HID * HID * 2);
    u16* wt3r = (u16*)alloc((size_t)HID * HID * 2);
    u16* wt3n = (u16*)alloc((size_t)HID * HID * 2);
    float* partial = (float*)alloc((size_t)N_GRAPHS * 8 * HID * 4);
    float* pooled  = (float*)alloc((size_t)N_GRAPHS * HID * 4);
    int* deg       = (int*)alloc((size_t)N_NODES * 4);
    int* row_start = (int*)alloc((size_t)(N_NODES + 1) * 4);
    int* cursor    = (int*)alloc((size_t)N_NODES * 4);
    int* esrc      = (int*)alloc((size_t)N_EDGES * 4);
    int* gstart    = (int*)alloc((size_t)(N_GRAPHS + 1) * 4);
    int* bsum      = (int*)alloc((size_t)SCAN_BLOCKS * 4);
    int* boff      = (int*)alloc((size_t)SCAN_BLOCKS * 4);

    const int EB = (N_EDGES + 255) / 256;

    // ---- CSR build ----
    hipMemsetAsync(deg, 0, N_NODES * sizeof(int), stream);
    hist_kernel<<<EB, 256, 0, stream>>>(dst, deg);
    scan_p1<<<SCAN_BLOCKS, 256, 0, stream>>>(deg, bsum);
    scan_p2<<<1, 256, 0, stream>>>(bsum, boff, row_start);
    scan_p3<<<SCAN_BLOCKS, 256, 0, stream>>>(deg, boff, row_start, cursor);
    fill_kernel<<<EB, 256, 0, stream>>>(src, dst, cursor, esrc);

    // ---- conversions ----
    cvt_x_kernel<<<(N_NODES * (IN_CH / 8) + 255) / 256, 256, 0, stream>>>(x, x_bf);
    twt_kernel<<<(2 * IN_CH * HID + 255) / 256, 256, 0, stream>>>(
        W1r, W1n, nullptr, nullptr, wt1r, wt1n, nullptr, nullptr, IN_CH, 2);
    twt_kernel<<<(4 * HID * HID + 255) / 256, 256, 0, stream>>>(
        W2r, W2n, W3r, W3n, wt2r, wt2n, wt3r, wt3n, HID, 4);

    dim3 gemm_grid((N_NODES + 127) / 128, HID / 128);

    // ---- layer 1 (K=128, relu) ----
    gather_bf<IN_CH><<<(N_NODES * (IN_CH / 8) / 256) + 1, 256, 0, stream>>>(x_bf, row_start, esrc, agg);
    mfma_gemm<1><<<gemm_grid, 256, 0, stream>>>(x_bf, agg, wt1r, wt1n, b1, hA, N_NODES, IN_CH);

    // ---- layer 2 (K=256, relu) ----
    gather_bf<HID><<<(N_NODES * (HID / 8) / 256) + 1, 256, 0, stream>>>(hA, row_start, esrc, agg);
    mfma_gemm<1><<<gemm_grid, 256, 0, stream>>>(hA, agg, wt2r, wt2n, b2, hB, N_NODES, HID);

    // ---- layer 3 (K=256, no relu) ----
    gather_bf<HID><<<(N_NODES * (HID / 8) / 256) + 1, 256, 0, stream>>>(hB, row_start, esrc, agg);
    mfma_gemm<0><<<gemm_grid, 256, 0, stream>>>(hB, agg, wt3r, wt3n, b3, hA, N_NODES, HID);

    // ---- pool + classifier ----
    graph_bounds_kernel<<<1, 128, 0, stream>>>(batch, gstart);
    pool1_kernel<<<N_GRAPHS * 8, HID, 0, stream>>>(hA, gstart, partial);
    pool2_kernel<<<N_GRAPHS, HID, 0, stream>>>(partial, gstart, pooled);
    final_kernel<<<N_GRAPHS, HID, 0, stream>>>(pooled, Wl, bl, out);
}

// Round 5
// 408.567 us; speedup vs baseline: 18.7571x; 1.0169x over previous
//
#include <hip/hip_runtime.h>
#include <stdint.h>

#define N_NODES 50000
#define N_EDGES 800000
#define IN_CH 128
#define HID 256
#define N_GRAPHS 64
#define N_CLASSES 10

#define SCAN_BLOCKS ((N_NODES + 255) / 256)   // 196
#define GEMM_MT ((N_NODES + 127) / 128)       // 391 row tiles
#define GEMM_WG (GEMM_MT * 2)                 // 782 blocks (2 col tiles)

typedef unsigned short u16;
typedef __attribute__((ext_vector_type(8))) short short8;
typedef __attribute__((ext_vector_type(4))) float f32x4;

__device__ __forceinline__ float bf2f(uint32_t u) {
    union { uint32_t i; float f; } v; v.i = u << 16; return v.f;
}
__device__ __forceinline__ uint32_t f2bf(float f) {
    union { float f; uint32_t i; } v; v.f = f;
    return (v.i + 0x7FFFu + ((v.i >> 16) & 1u)) >> 16;   // RNE
}

// ===========================================================================
// CSR build
// ===========================================================================
__global__ void hist_kernel(const int* __restrict__ dst, int* __restrict__ deg)
{
    int e = blockIdx.x * blockDim.x + threadIdx.x;
    if (e < N_EDGES) atomicAdd(&deg[dst[e]], 1);
}

__global__ void __launch_bounds__(256) scan_p1(const int* __restrict__ deg, int* __restrict__ bsum)
{
    __shared__ int buf[256];
    int i = blockIdx.x * 256 + threadIdx.x;
    int v = (i < N_NODES) ? deg[i] : 0;
    buf[threadIdx.x] = v;
    __syncthreads();
    #pragma unroll
    for (int off = 128; off > 0; off >>= 1) {
        if (threadIdx.x < off) buf[threadIdx.x] += buf[threadIdx.x + off];
        __syncthreads();
    }
    if (threadIdx.x == 0) bsum[blockIdx.x] = buf[0];
}

__global__ void __launch_bounds__(256) scan_p2(const int* __restrict__ bsum,
                                               int* __restrict__ boff,
                                               int* __restrict__ row_start)
{
    __shared__ int buf[256];
    int t = threadIdx.x;
    int v = (t < SCAN_BLOCKS) ? bsum[t] : 0;
    buf[t] = v;
    __syncthreads();
    #pragma unroll
    for (int off = 1; off < 256; off <<= 1) {
        int a = (t >= off) ? buf[t - off] : 0;
        __syncthreads();
        buf[t] += a;
        __syncthreads();
    }
    if (t < SCAN_BLOCKS) boff[t] = buf[t] - v;
    if (t == 255) row_start[N_NODES] = buf[255];
}

__global__ void __launch_bounds__(256) scan_p3(const int* __restrict__ deg,
                                               const int* __restrict__ boff,
                                               int* __restrict__ row_start,
                                               int* __restrict__ cursor)
{
    __shared__ int buf[256];
    int t = threadIdx.x;
    int i = blockIdx.x * 256 + t;
    int v = (i < N_NODES) ? deg[i] : 0;
    buf[t] = v;
    __syncthreads();
    #pragma unroll
    for (int off = 1; off < 256; off <<= 1) {
        int a = (t >= off) ? buf[t - off] : 0;
        __syncthreads();
        buf[t] += a;
        __syncthreads();
    }
    if (i < N_NODES) {
        int rs = boff[blockIdx.x] + buf[t] - v;
        row_start[i] = rs;
        cursor[i] = rs;
    }
}

__global__ void fill_kernel(const int* __restrict__ src, const int* __restrict__ dst,
                            int* __restrict__ cursor, int* __restrict__ esrc)
{
    int e = blockIdx.x * blockDim.x + threadIdx.x;
    if (e < N_EDGES) {
        int pos = atomicAdd(&cursor[dst[e]], 1);
        esrc[pos] = src[e];
    }
}

// ===========================================================================
// fp32 -> bf16 conversions
// ===========================================================================
__global__ void cvt_x_kernel(const float* __restrict__ x, u16* __restrict__ xb)
{
    int id = blockIdx.x * blockDim.x + threadIdx.x;
    if (id >= N_NODES * (IN_CH / 8)) return;
    const float4 a = *reinterpret_cast<const float4*>(x + (size_t)id * 8);
    const float4 b = *reinterpret_cast<const float4*>(x + (size_t)id * 8 + 4);
    uint4 o;
    o.x = f2bf(a.x) | (f2bf(a.y) << 16);
    o.y = f2bf(a.z) | (f2bf(a.w) << 16);
    o.z = f2bf(b.x) | (f2bf(b.y) << 16);
    o.w = f2bf(b.z) | (f2bf(b.w) << 16);
    *reinterpret_cast<uint4*>(xb + (size_t)id * 8) = o;
}

__global__ void twt_kernel(const float* W0, const float* W1, const float* W2, const float* W3,
                           u16* o0, u16* o1, u16* o2, u16* o3, int K, int nmat)
{
    int id = blockIdx.x * blockDim.x + threadIdx.x;
    int per = K * HID;
    int m = id / per;
    if (m >= nmat) return;
    int r = id % per;
    int k = r / HID, n = r % HID;
    const float* W = (m == 0) ? W0 : (m == 1) ? W1 : (m == 2) ? W2 : W3;
    u16* O = (m == 0) ? o0 : (m == 1) ? o1 : (m == 2) ? o2 : o3;
    O[(size_t)n * K + k] = (u16)f2bf(W[r]);
}

// ===========================================================================
// agg[i,:] = sum_{j in in(i)} feat[j,:]  — bf16, fp32 acc, 4-deep unroll
// ===========================================================================
template<int D>
__global__ void __launch_bounds__(256)
gather_bf(const u16* __restrict__ feat, const int* __restrict__ row_start,
          const int* __restrict__ esrc, u16* __restrict__ agg)
{
    constexpr int GS = D / 8;
    constexpr int NPB = 256 / GS;
    int node = blockIdx.x * NPB + threadIdx.x / GS;
    int lane = threadIdx.x % GS;
    if (node >= N_NODES) return;
    const int s = row_start[node], e = row_start[node + 1];
    float acc[8] = {0.f, 0.f, 0.f, 0.f, 0.f, 0.f, 0.f, 0.f};
    const u16* fp = feat + lane * 8;

    auto add = [&](uint4 v) {
        acc[0] += bf2f(v.x & 0xFFFF); acc[1] += bf2f(v.x >> 16);
        acc[2] += bf2f(v.y & 0xFFFF); acc[3] += bf2f(v.y >> 16);
        acc[4] += bf2f(v.z & 0xFFFF); acc[5] += bf2f(v.z >> 16);
        acc[6] += bf2f(v.w & 0xFFFF); acc[7] += bf2f(v.w >> 16);
    };

    int j = s;
    for (; j + 3 < e; j += 4) {
        int s0 = esrc[j], s1 = esrc[j + 1], s2 = esrc[j + 2], s3 = esrc[j + 3];
        uint4 v0 = *reinterpret_cast<const uint4*>(fp + (size_t)s0 * D);
        uint4 v1 = *reinterpret_cast<const uint4*>(fp + (size_t)s1 * D);
        uint4 v2 = *reinterpret_cast<const uint4*>(fp + (size_t)s2 * D);
        uint4 v3 = *reinterpret_cast<const uint4*>(fp + (size_t)s3 * D);
        add(v0); add(v1); add(v2); add(v3);
    }
    for (; j < e; ++j) {
        uint4 v0 = *reinterpret_cast<const uint4*>(fp + (size_t)esrc[j] * D);
        add(v0);
    }
    uint4 o;
    o.x = f2bf(acc[0]) | (f2bf(acc[1]) << 16);
    o.y = f2bf(acc[2]) | (f2bf(acc[3]) << 16);
    o.z = f2bf(acc[4]) | (f2bf(acc[5]) << 16);
    o.w = f2bf(acc[6]) | (f2bf(acc[7]) << 16);
    *reinterpret_cast<uint4*>(agg + (size_t)node * D + lane * 8) = o;
}

// ===========================================================================
// C[m,n] = act( A1@W1 + A2@W2 + bias )   — bf16 MFMA, fp32 acc, bf16 out
// 1-D grid: wg -> (bm = wg>>1, bn = wg&1) after bijective XCD chunking so
// both column-tiles of a row-panel run on the same XCD (A L2 reuse).
// ===========================================================================
template<int RELU>
__global__ void __launch_bounds__(256)
mfma_gemm(const u16* __restrict__ A1, const u16* __restrict__ A2,
          const u16* __restrict__ B1t, const u16* __restrict__ B2t,
          const float* __restrict__ bias,
          u16* __restrict__ C,
          int M, int K)
{
    __shared__ __align__(16) u16 As[128][40];
    __shared__ __align__(16) u16 Bs[128][40];

    // bijective XCD chunking (m204): orig -> contiguous chunk per XCD
    const int orig = blockIdx.x;
    const int q = GEMM_WG / 8, r = GEMM_WG % 8;
    const int xcd = orig % 8;
    const int wg = (xcd < r ? xcd * (q + 1) : r * (q + 1) + (xcd - r) * q) + orig / 8;

    const int tid = threadIdx.x;
    const int bm = (wg >> 1) * 128;
    const int bn = (wg & 1) * 128;
    const int w  = tid >> 6;
    const int wm = (w >> 1) * 64;
    const int wn = (w & 1) * 64;
    const int l  = tid & 63;
    const int lr = l & 15;
    const int kb = (l >> 4) * 8;

    f32x4 acc[4][4];
    #pragma unroll
    for (int i = 0; i < 4; ++i)
        #pragma unroll
        for (int j = 0; j < 4; ++j)
            acc[i][j] = (f32x4){0.f, 0.f, 0.f, 0.f};

    const int row_s = tid >> 2;
    const int c8    = (tid & 3) * 8;

    for (int mat = 0; mat < 2; ++mat) {
        const u16* __restrict__ Ag = mat ? A2 : A1;
        const u16* __restrict__ Bg = mat ? B2t : B1t;
        for (int k0 = 0; k0 < K; k0 += 32) {
            #pragma unroll
            for (int it = 0; it < 2; ++it) {
                int row = row_s + it * 64;
                uint4 va = make_uint4(0u, 0u, 0u, 0u);
                int gr = bm + row;
                if (gr < M)
                    va = *reinterpret_cast<const uint4*>(Ag + (size_t)gr * K + k0 + c8);
                *reinterpret_cast<uint4*>(&As[row][c8]) = va;
                uint4 vb = *reinterpret_cast<const uint4*>(Bg + (size_t)(bn + row) * K + k0 + c8);
                *reinterpret_cast<uint4*>(&Bs[row][c8]) = vb;
            }
            __syncthreads();
            short8 af[4], bfr[4];
            #pragma unroll
            for (int f = 0; f < 4; ++f) {
                af[f]  = *reinterpret_cast<const short8*>(&As[wm + f * 16 + lr][kb]);
                bfr[f] = *reinterpret_cast<const short8*>(&Bs[wn + f * 16 + lr][kb]);
            }
            #pragma unroll
            for (int fm = 0; fm < 4; ++fm)
                #pragma unroll
                for (int fn = 0; fn < 4; ++fn)
                    acc[fm][fn] = __builtin_amdgcn_mfma_f32_16x16x32_bf16(
                        af[fm], bfr[fn], acc[fm][fn], 0, 0, 0);
            __syncthreads();
        }
    }

    const int r4 = (l >> 4) * 4;
    #pragma unroll
    for (int fm = 0; fm < 4; ++fm) {
        #pragma unroll
        for (int rr = 0; rr < 4; ++rr) {
            int row = bm + wm + fm * 16 + r4 + rr;
            if (row >= M) continue;
            #pragma unroll
            for (int fn = 0; fn < 4; ++fn) {
                int col = bn + wn + fn * 16 + lr;
                float v = acc[fm][fn][rr] + bias[col];
                if (RELU) v = fmaxf(v, 0.f);
                C[(size_t)row * HID + col] = (u16)f2bf(v);
            }
        }
    }
}

// ===========================================================================
// Pooling (batch sorted): inline binary search, two-stage mean
// ===========================================================================
__device__ __forceinline__ int lower_bound_g(const int* __restrict__ batch, int g)
{
    int lo = 0, hi = N_NODES;
    while (lo < hi) {
        int mid = (lo + hi) >> 1;
        if (batch[mid] < g) lo = mid + 1; else hi = mid;
    }
    return lo;
}

__global__ void pool1_kernel(const u16* __restrict__ h, const int* __restrict__ batch,
                             float* __restrict__ partial)
{
    int g = blockIdx.x >> 3;
    int c = blockIdx.x & 7;
    int t = threadIdx.x;      // 256
    int s = lower_bound_g(batch, g);
    int e = lower_bound_g(batch, g + 1);
    int cnt = e - s;
    int a = s + (int)(((long long)cnt * c) >> 3);
    int b = s + (int)(((long long)cnt * (c + 1)) >> 3);
    float acc = 0.f;
    for (int i = a; i < b; ++i)
        acc += bf2f(h[(size_t)i * HID + t]);
    partial[(size_t)blockIdx.x * HID + t] = acc;
}

__global__ void pool2_kernel(const float* __restrict__ partial, const int* __restrict__ batch,
                             float* __restrict__ pooled)
{
    int g = blockIdx.x;
    int t = threadIdx.x;
    float acc = 0.f;
    #pragma unroll
    for (int c = 0; c < 8; ++c)
        acc += partial[(size_t)(g * 8 + c) * HID + t];
    float cnt = fmaxf((float)(lower_bound_g(batch, g + 1) - lower_bound_g(batch, g)), 1.f);
    pooled[g * HID + t] = acc / cnt;
}

__global__ void final_kernel(const float* __restrict__ pooled,
                             const float* __restrict__ W_lin,
                             const float* __restrict__ b_lin,
                             float* __restrict__ out)
{
    __shared__ float v[HID];
    int g = blockIdx.x;
    int t = threadIdx.x;
    v[t] = pooled[g * HID + t];
    __syncthreads();
    if (t < N_CLASSES) {
        float s = b_lin[t];
        for (int k = 0; k < HID; ++k)
            s += v[k] * W_lin[k * N_CLASSES + t];
        out[g * N_CLASSES + t] = s;
    }
}

// ===========================================================================
extern "C" void kernel_launch(void* const* d_in, const int* in_sizes, int n_in,
                              void* d_out, int out_size, void* d_ws, size_t ws_size,
                              hipStream_t stream)
{
    const float* x     = (const float*)d_in[0];
    const int*   ei    = (const int*)d_in[1];
    const int*   batch = (const int*)d_in[2];
    const float* W1r = (const float*)d_in[3];
    const float* W1n = (const float*)d_in[4];
    const float* b1  = (const float*)d_in[5];
    const float* W2r = (const float*)d_in[6];
    const float* W2n = (const float*)d_in[7];
    const float* b2  = (const float*)d_in[8];
    const float* W3r = (const float*)d_in[9];
    const float* W3n = (const float*)d_in[10];
    const float* b3  = (const float*)d_in[11];
    const float* Wl  = (const float*)d_in[12];
    const float* bl  = (const float*)d_in[13];
    float* out = (float*)d_out;

    const int* src = ei;
    const int* dst = ei + N_EDGES;

    char* base = (char*)d_ws;
    size_t off = 0;
    auto alloc = [&](size_t bytes) { char* p = base + off; off += (bytes + 255) & ~(size_t)255; return p; };
    u16* x_bf = (u16*)alloc((size_t)N_NODES * IN_CH * 2);
    u16* hA   = (u16*)alloc((size_t)N_NODES * HID * 2);
    u16* hB   = (u16*)alloc((size_t)N_NODES * HID * 2);
    u16* agg  = (u16*)alloc((size_t)N_NODES * HID * 2);
    u16* wt1r = (u16*)alloc((size_t)HID * IN_CH * 2);
    u16* wt1n = (u16*)alloc((size_t)HID * IN_CH * 2);
    u16* wt2r = (u16*)alloc((size_t)HID * HID * 2);
    u16* wt2n = (u16*)alloc((size_t)HID * HID * 2);
    u16* wt3r = (u16*)alloc((size_t)HID * HID * 2);
    u16* wt3n = (u16*)alloc((size_t)HID * HID * 2);
    float* partial = (float*)alloc((size_t)N_GRAPHS * 8 * HID * 4);
    float* pooled  = (float*)alloc((size_t)N_GRAPHS * HID * 4);
    int* deg       = (int*)alloc((size_t)N_NODES * 4);
    int* row_start = (int*)alloc((size_t)(N_NODES + 1) * 4);
    int* cursor    = (int*)alloc((size_t)N_NODES * 4);
    int* esrc      = (int*)alloc((size_t)N_EDGES * 4);
    int* bsum      = (int*)alloc((size_t)SCAN_BLOCKS * 4);
    int* boff      = (int*)alloc((size_t)SCAN_BLOCKS * 4);

    const int EB = (N_EDGES + 255) / 256;

    // ---- CSR build ----
    hipMemsetAsync(deg, 0, N_NODES * sizeof(int), stream);
    hist_kernel<<<EB, 256, 0, stream>>>(dst, deg);
    scan_p1<<<SCAN_BLOCKS, 256, 0, stream>>>(deg, bsum);
    scan_p2<<<1, 256, 0, stream>>>(bsum, boff, row_start);
    scan_p3<<<SCAN_BLOCKS, 256, 0, stream>>>(deg, boff, row_start, cursor);
    fill_kernel<<<EB, 256, 0, stream>>>(src, dst, cursor, esrc);

    // ---- conversions ----
    cvt_x_kernel<<<(N_NODES * (IN_CH / 8) + 255) / 256, 256, 0, stream>>>(x, x_bf);
    twt_kernel<<<(2 * IN_CH * HID + 255) / 256, 256, 0, stream>>>(
        W1r, W1n, nullptr, nullptr, wt1r, wt1n, nullptr, nullptr, IN_CH, 2);
    twt_kernel<<<(4 * HID * HID + 255) / 256, 256, 0, stream>>>(
        W2r, W2n, W3r, W3n, wt2r, wt2n, wt3r, wt3n, HID, 4);

    // ---- layer 1 (K=128, relu) ----
    gather_bf<IN_CH><<<(N_NODES * (IN_CH / 8) / 256) + 1, 256, 0, stream>>>(x_bf, row_start, esrc, agg);
    mfma_gemm<1><<<GEMM_WG, 256, 0, stream>>>(x_bf, agg, wt1r, wt1n, b1, hA, N_NODES, IN_CH);

    // ---- layer 2 (K=256, relu) ----
    gather_bf<HID><<<(N_NODES * (HID / 8) / 256) + 1, 256, 0, stream>>>(hA, row_start, esrc, agg);
    mfma_gemm<1><<<GEMM_WG, 256, 0, stream>>>(hA, agg, wt2r, wt2n, b2, hB, N_NODES, HID);

    // ---- layer 3 (K=256, no relu) ----
    gather_bf<HID><<<(N_NODES * (HID / 8) / 256) + 1, 256, 0, stream>>>(hB, row_start, esrc, agg);
    mfma_gemm<0><<<GEMM_WG, 256, 0, stream>>>(hB, agg, wt3r, wt3n, b3, hA, N_NODES, HID);

    // ---- pool + classifier ----
    pool1_kernel<<<N_GRAPHS * 8, HID, 0, stream>>>(hA, batch, partial);
    pool2_kernel<<<N_GRAPHS, HID, 0, stream>>>(partial, batch, pooled);
    final_kernel<<<N_GRAPHS, HID, 0, stream>>>(pooled, Wl, bl, out);
}